// Round 6
// baseline (463.742 us; speedup 1.0000x reference)
//
#include <hip/hip_runtime.h>
#include <cstdint>
#include <cmath>

#define N_HEADS 16
#define I_DIM 128
#define H_DIM 128
#define B_SZ 16
#define T_SZ 512
#define G3 384           // 3*H
#define BT (B_SZ * T_SZ) // 8192
#define LDW 136          // padded LDS row stride in bf16 (128+8), keeps 16B align
#define OUT_HN_OFFSET ((size_t)B_SZ * T_SZ * (N_HEADS * H_DIM)) // 16777216
#define CHUNK 8
#define NCHUNK (T_SZ / CHUNK) // 64
#define HPAD 160            // h2 parity stride in ushorts (320B -> disjoint banks)

typedef __attribute__((ext_vector_type(8))) short bf16x8;
typedef __attribute__((ext_vector_type(4))) float f32x4;

static __device__ __forceinline__ unsigned short f2bf(float f) {
  unsigned int u = __float_as_uint(f);
  unsigned int r = (u + 0x7FFFu + ((u >> 16) & 1u)) >> 16; // RNE
  return (unsigned short)r;
}
static __device__ __forceinline__ float bf2f(unsigned short s) {
  return __uint_as_float((unsigned int)s << 16);
}
static __device__ __forceinline__ uint2 pack4(float4 v) {
  uint2 p;
  p.x = (unsigned int)f2bf(v.x) | ((unsigned int)f2bf(v.y) << 16);
  p.y = (unsigned int)f2bf(v.z) | ((unsigned int)f2bf(v.w) << 16);
  return p;
}
static __device__ __forceinline__ bf16x8 pack8(float4 a, float4 b) {
  union { uint2 u[2]; bf16x8 v; } r;
  r.u[0] = pack4(a);
  r.u[1] = pack4(b);
  return r.v;
}

// ---------------------------------------------------------------------------
// Kernel A — REVERTED to the R2 version (best-measured pairing: 421.7us
// total). R4/R5 post-mortems: transposed stores (R4) and reg-W/2WG-CU (R5)
// both made A slightly WORSE (A+gap 124->132->139us); all A theories so far
// (pack-VALU, store transactions, occupancy) are refuted, so A returns to
// the known-best config: 1 WG/CU, full W_ih[n] in 104KB LDS staged once,
// 8 X-tiles, gates layout [N][BT][G3] (scattered u16 stores).
// ---------------------------------------------------------------------------
__global__ __launch_bounds__(256) void gates_x_mfma(
    const float* __restrict__ x, const float* __restrict__ w_ih,
    const float* __restrict__ b_ih, unsigned short* __restrict__ gates) {
  const int n = blockIdx.z;
  const int grp = blockIdx.x; // 0..15, 8 tiles of 64 bt-rows each
  const int tid = threadIdx.x;
  const int wave = tid >> 6;
  const int lane = tid & 63;
  const int m16 = lane & 15;
  const int quad = lane >> 4;

  extern __shared__ __align__(16) unsigned short lds_pool[];
  unsigned short* Ws = lds_pool;            // G3*LDW ushorts = 104,448 B
  unsigned short* Xs = lds_pool + G3 * LDW; // 64*LDW ushorts =  17,408 B

  const int xrow = tid >> 2;
  const int xq = tid & 3;

  float4 xf[8];
  {
    const float4* xg =
        (const float4*)(x + (size_t)(grp * 512 + xrow) * 2048 + n * I_DIM) +
        xq * 8;
#pragma unroll
    for (int i = 0; i < 8; ++i) xf[i] = xg[i];
  }

  {
    const float4* wsrc = (const float4*)(w_ih + (size_t)n * G3 * I_DIM);
#pragma unroll
    for (int i = 0; i < 48; ++i) {
      const int idx = i * 256 + tid; // f4 index
      *(uint2*)&Ws[(idx >> 5) * LDW + (idx & 31) * 4] = pack4(wsrc[idx]);
    }
  }

  float bias[3][8];
#pragma unroll
  for (int gb = 0; gb < 3; ++gb)
#pragma unroll
    for (int j = 0; j < 8; ++j)
      bias[gb][j] = b_ih[n * G3 + gb * 128 + j * 16 + m16];

  for (int tile = 0; tile < 8; ++tile) {
    const int bt0 = grp * 512 + tile * 64;

    __syncthreads();
#pragma unroll
    for (int i = 0; i < 8; ++i)
      *(uint2*)&Xs[xrow * LDW + xq * 32 + i * 4] = pack4(xf[i]);
    __syncthreads();

    if (tile < 7) {
      const float4* xg =
          (const float4*)(x + (size_t)(bt0 + 64 + xrow) * 2048 + n * I_DIM) +
          xq * 8;
#pragma unroll
      for (int i = 0; i < 8; ++i) xf[i] = xg[i];
    }

#pragma unroll
    for (int gb = 0; gb < 3; ++gb) {
      f32x4 acc[8];
#pragma unroll
      for (int j = 0; j < 8; ++j) acc[j] = (f32x4){0.f, 0.f, 0.f, 0.f};

#pragma unroll
      for (int kt = 0; kt < 4; ++kt) {
        const bf16x8 afrag =
            *(const bf16x8*)&Xs[(wave * 16 + m16) * LDW + kt * 32 + quad * 8];
#pragma unroll
        for (int j = 0; j < 8; ++j) {
          const bf16x8 bfrag =
              *(const bf16x8*)&Ws[(gb * 128 + j * 16 + m16) * LDW + kt * 32 +
                                  quad * 8];
          acc[j] = __builtin_amdgcn_mfma_f32_16x16x32_bf16(afrag, bfrag,
                                                           acc[j], 0, 0, 0);
        }
      }

#pragma unroll
      for (int j = 0; j < 8; ++j) {
        const int g = gb * 128 + j * 16 + m16;
#pragma unroll
        for (int r = 0; r < 4; ++r) {
          const int bt = bt0 + wave * 16 + quad * 4 + r;
          gates[((size_t)n * BT + bt) * G3 + g] =
              f2bf(acc[j][r] + bias[gb][j]);
        }
      }
    }
  }
}

// ---------------------------------------------------------------------------
// Kernel B v7: producer-wave MFMA scan. 576 thr = 8 compute waves + 1
// producer wave. One WG per (b,n).
//
// R5 post-mortem: step stuck ~1390cy across 3 structures; TLP doesn't help
// because the binding structure is per-step serial: barrier + LDS h
// round-trip + dependent MFMA chain + __syncthreads' vmcnt(0) draining the
// chunk-boundary global ops (~500-900cy on the collective path 2x/chunk).
// vmcnt is PER-WAVE -> fixes:
//  * Wave 8 = producer: does ALL global ops (gate chunks 2-deep in regs ->
//    scatter to gbuf; out stores from an LDS obuf). Its vmcnt(0) stalls
//    overlap compute work. Compute waves: ZERO global ops in the loop ->
//    their step barriers drain nothing.
//  * h2 parity stride 320B -> hi/lo b128 reads hit disjoint bank halves
//    (kills the 18.3M bank conflicts).
//  * 4 independent per-kt accumulators (+VALU tree) instead of a 4-deep
//    dependent MFMA chain.
// Per-element math identical to v6 (kt-partial fp32 sum order differs).
// ---------------------------------------------------------------------------
__global__ __launch_bounds__(576, 1) void gru_scan_kernel(
    const float* __restrict__ h0, const float* __restrict__ w_hh,
    const float* __restrict__ b_hh, const unsigned short* __restrict__ gates,
    float* __restrict__ out) {
  const int b = blockIdx.x >> 4;
  const int n = blockIdx.x & 15;
  const int tid = threadIdx.x;
  const int wave = tid >> 6;
  const int lane = tid & 63;
  const int m16 = lane & 15;
  const int quad = lane >> 4;

  __shared__ __align__(16) unsigned short h2[2][2][HPAD];       // [buf][hi|lo]
  __shared__ __align__(16) unsigned short gbuf[2][CHUNK * 512]; // [s][e][4]
  __shared__ __align__(16) float obuf[2][CHUNK][H_DIM];         // staged out

  const bool is_comp = wave < 8;
  const bool upd = is_comp && (quad == 0); // 128 updating lanes
  const int elem = (is_comp ? wave * 16 : 0) + m16;

  // ---- compute-wave init: register-resident W_hh B-fragments ----
  // Wave w (0..7) colblocks {w, 8+w, 16+w} -> r/z/n rows for elems w*16+m16.
  bf16x8 wf[3][4];
  if (is_comp) {
    const int cbs[3] = {wave, 8 + wave, 16 + wave};
#pragma unroll
    for (int j = 0; j < 3; ++j) {
      const int g = cbs[j] * 16 + m16;
      const float4* wr = (const float4*)(w_hh + ((size_t)n * G3 + g) * H_DIM);
#pragma unroll
      for (int kt = 0; kt < 4; ++kt)
        wf[j][kt] = pack8(wr[kt * 8 + quad * 2], wr[kt * 8 + quad * 2 + 1]);
    }
  }

  float bh_r = 0.f, bh_z = 0.f, bh_n = 0.f, h_old = 0.f;
  if (upd) {
    bh_r = b_hh[n * G3 + elem];
    bh_z = b_hh[n * G3 + elem + 128];
    bh_n = b_hh[n * G3 + elem + 256];
    h_old = h0[(size_t)b * 2048 + n * H_DIM + elem];
    const unsigned short hh = f2bf(h_old);
    h2[0][0][elem] = hh;
    h2[0][1][elem] = f2bf(h_old - bf2f(hh));
  }

  const unsigned short* gx_base =
      gates + ((size_t)n * BT + (size_t)b * T_SZ) * G3; // [bt][g] contiguous
  float* out_base = out + (size_t)b * T_SZ * 2048 + n * H_DIM;

  // Scatter a chunk (6KB = [s][g] row-major) into gbuf layout [s][e][{r,z,n,_}].
  auto scatter6 = [&](unsigned short* buf, const uint4* v) {
#pragma unroll
    for (int j = 0; j < 6; ++j) {
      const int k = j * 64 + lane; // uint4 index within chunk (48 per step)
      const int s = k / 48;
      const int g0 = (k - s * 48) * 8;
      unsigned short* d = buf + s * 512;
      const unsigned int w[4] = {v[j].x, v[j].y, v[j].z, v[j].w};
#pragma unroll
      for (int i = 0; i < 8; ++i) {
        const int g = g0 + i;
        d[(g & 127) * 4 + (g >> 7)] =
            (unsigned short)((i & 1) ? (w[i >> 1] >> 16) : w[i >> 1]);
      }
    }
  };

  // ---- producer prologue: chunk 0 staged, chunk 1 in regs ----
  uint4 pfv[6];
  if (!is_comp) {
    uint4 c0[6];
#pragma unroll
    for (int j = 0; j < 6; ++j)
      c0[j] = ((const uint4*)gx_base)[j * 64 + lane];
    scatter6(gbuf[0], c0);
#pragma unroll
    for (int j = 0; j < 6; ++j)
      pfv[j] = ((const uint4*)(gx_base + (size_t)CHUNK * G3))[j * 64 + lane];
  }
  __syncthreads();

  for (int c = 0; c < NCHUNK; ++c) {
    const int gb = c & 1;

    if (!is_comp) {
      // Store chunk c-1 outputs (LDS -> HBM): lane covers 16 floats of row s.
      if (c >= 1) {
        const int ob = (c - 1) & 1;
        const int s = lane >> 3;
        const int col = (lane & 7) * 16;
        const float4* src = (const float4*)&obuf[ob][s][col];
        const float4 v0 = src[0], v1 = src[1], v2 = src[2], v3 = src[3];
        float* dst = out_base + (size_t)((c - 1) * CHUNK + s) * 2048 + col;
        *(float4*)&dst[0] = v0;
        *(float4*)&dst[4] = v1;
        *(float4*)&dst[8] = v2;
        *(float4*)&dst[12] = v3;
      }
      // Scatter chunk c+1 (loaded a chunk ago -> vmcnt long satisfied).
      if (c + 1 < NCHUNK) scatter6(gbuf[gb ^ 1], pfv);
      // Issue chunk c+2 loads (retire over the next ~8 steps).
      if (c + 2 < NCHUNK) {
        const unsigned short* gch = gx_base + (size_t)(c + 2) * CHUNK * G3;
#pragma unroll
        for (int j = 0; j < 6; ++j)
          pfv[j] = ((const uint4*)gch)[j * 64 + lane];
      }
    }

#pragma unroll
    for (int s = 0; s < CHUNK; ++s) {
      const int rb = s & 1; // chunk length even -> parity restarts at 0
      const int wb = rb ^ 1;

      float gxr = 0.f, gxz = 0.f, gxn = 0.f;
      bf16x8 av0, av1, av2, av3;
      if (is_comp) {
        if (upd) {
          const uint2 gxu = *(const uint2*)&gbuf[gb][s * 512 + elem * 4];
          gxr = __uint_as_float(gxu.x << 16);
          gxz = __uint_as_float(gxu.x & 0xffff0000u);
          gxn = __uint_as_float(gxu.y << 16);
        }
        const unsigned short* hsrc = &h2[rb][m16 & 1][0];
        av0 = *(const bf16x8*)&hsrc[0 * 32 + quad * 8];
        av1 = *(const bf16x8*)&hsrc[1 * 32 + quad * 8];
        av2 = *(const bf16x8*)&hsrc[2 * 32 + quad * 8];
        av3 = *(const bf16x8*)&hsrc[3 * 32 + quad * 8];

        // Independent per-kt accumulators: no dependent MFMA chain.
        f32x4 acc[3][4];
#pragma unroll
        for (int j = 0; j < 3; ++j)
#pragma unroll
          for (int kt = 0; kt < 4; ++kt) acc[j][kt] = (f32x4){0.f, 0.f, 0.f, 0.f};
#pragma unroll
        for (int j = 0; j < 3; ++j) {
          acc[j][0] = __builtin_amdgcn_mfma_f32_16x16x32_bf16(av0, wf[j][0],
                                                              acc[j][0], 0, 0, 0);
          acc[j][1] = __builtin_amdgcn_mfma_f32_16x16x32_bf16(av1, wf[j][1],
                                                              acc[j][1], 0, 0, 0);
          acc[j][2] = __builtin_amdgcn_mfma_f32_16x16x32_bf16(av2, wf[j][2],
                                                              acc[j][2], 0, 0, 0);
          acc[j][3] = __builtin_amdgcn_mfma_f32_16x16x32_bf16(av3, wf[j][3],
                                                              acc[j][3], 0, 0, 0);
        }

        if (upd) {
          // D[0]=W.h_hi, D[1]=W.h_lo per kt; sum kt partials (VALU tree).
          const float ghr = ((acc[0][0][0] + acc[0][1][0]) +
                             (acc[0][2][0] + acc[0][3][0])) +
                            ((acc[0][0][1] + acc[0][1][1]) +
                             (acc[0][2][1] + acc[0][3][1])) + bh_r;
          const float ghz = ((acc[1][0][0] + acc[1][1][0]) +
                             (acc[1][2][0] + acc[1][3][0])) +
                            ((acc[1][0][1] + acc[1][1][1]) +
                             (acc[1][2][1] + acc[1][3][1])) + bh_z;
          const float ghn = ((acc[2][0][0] + acc[2][1][0]) +
                             (acc[2][2][0] + acc[2][3][0])) +
                            ((acc[2][0][1] + acc[2][1][1]) +
                             (acc[2][2][1] + acc[2][3][1])) + bh_n;
          const float r = 1.f / (1.f + __expf(-(gxr + ghr)));
          const float z = 1.f / (1.f + __expf(-(gxz + ghz)));
          const float targ = gxn + r * ghn;
          const float rt = 1.f / (1.f + __expf(-2.f * targ)); // sigmoid(2x)
          const float nn = 2.f * rt - 1.f;                    // tanh(targ)
          const float hn = (1.f - z) * nn + z * h_old;
          const unsigned short hh = f2bf(hn);
          h2[wb][0][elem] = hh;
          h2[wb][1][elem] = f2bf(hn - bf2f(hh));
          h_old = hn;
          obuf[gb][s][elem] = hn; // LDS only; producer does the HBM store
        }
      }
      __syncthreads();
    }
  }

  // Tail: last chunk's outputs + h_n.
  if (!is_comp) {
    const int ob = (NCHUNK - 1) & 1;
    const int s = lane >> 3;
    const int col = (lane & 7) * 16;
    const float4* src = (const float4*)&obuf[ob][s][col];
    const float4 v0 = src[0], v1 = src[1], v2 = src[2], v3 = src[3];
    float* dst = out_base + (size_t)((NCHUNK - 1) * CHUNK + s) * 2048 + col;
    *(float4*)&dst[0] = v0;
    *(float4*)&dst[4] = v1;
    *(float4*)&dst[8] = v2;
    *(float4*)&dst[12] = v3;
  }
  if (upd) {
    out[OUT_HN_OFFSET + (size_t)b * 2048 + n * H_DIM + elem] = h_old;
  }
}

extern "C" void kernel_launch(void* const* d_in, const int* in_sizes, int n_in,
                              void* d_out, int out_size, void* d_ws,
                              size_t ws_size, hipStream_t stream) {
  const float* x    = (const float*)d_in[0]; // [B, T, N*I]
  const float* h0   = (const float*)d_in[1]; // [1, B, N*H]
  const float* w_ih = (const float*)d_in[2]; // [N, 3H, I]
  const float* w_hh = (const float*)d_in[3]; // [N, 3H, H]
  const float* b_ih = (const float*)d_in[4]; // [N, 3H]
  const float* b_hh = (const float*)d_in[5]; // [N, 3H]
  float* out = (float*)d_out;
  unsigned short* gates = (unsigned short*)d_ws; // [N][BT][G3] bf16 = 96 MB

  // Kernel A uses 122 KB LDS (full W_ih[n] resident): opt in past 64 KB.
  static bool lds_opt_in = false;
  if (!lds_opt_in) {
    (void)hipFuncSetAttribute(reinterpret_cast<const void*>(&gates_x_mfma),
                              hipFuncAttributeMaxDynamicSharedMemorySize,
                              (G3 + 64) * LDW * (int)sizeof(unsigned short));
    lds_opt_in = true;
  }

  dim3 gridA(16, 1, N_HEADS);
  gates_x_mfma<<<gridA, 256, (G3 + 64) * LDW * sizeof(unsigned short),
                 stream>>>(x, w_ih, b_ih, gates);
  gru_scan_kernel<<<256, 576, 0, stream>>>(h0, w_hh, b_hh, gates, out);
}

// Round 8
// 431.586 us; speedup vs baseline: 1.0745x; 1.0745x over previous
//
#include <hip/hip_runtime.h>
#include <cstdint>
#include <cmath>

#define N_HEADS 16
#define I_DIM 128
#define H_DIM 128
#define B_SZ 16
#define T_SZ 512
#define G3 384           // 3*H
#define OUT_HN_OFFSET ((size_t)B_SZ * T_SZ * (N_HEADS * H_DIM)) // 16777216
#define CHUNK 8
#define NCHUNK (T_SZ / CHUNK) // 64
#define HPAD 160             // h2 parity stride in ushorts (320B -> disjoint banks)

typedef __attribute__((ext_vector_type(8))) short bf16x8;
typedef __attribute__((ext_vector_type(4))) float f32x4;

static __device__ __forceinline__ unsigned short f2bf(float f) {
  unsigned int u = __float_as_uint(f);
  unsigned int r = (u + 0x7FFFu + ((u >> 16) & 1u)) >> 16; // RNE
  return (unsigned short)r;
}
static __device__ __forceinline__ float bf2f(unsigned short s) {
  return __uint_as_float((unsigned int)s << 16);
}
static __device__ __forceinline__ uint2 pack4(float4 v) {
  uint2 p;
  p.x = (unsigned int)f2bf(v.x) | ((unsigned int)f2bf(v.y) << 16);
  p.y = (unsigned int)f2bf(v.z) | ((unsigned int)f2bf(v.w) << 16);
  return p;
}
static __device__ __forceinline__ bf16x8 pack8(float4 a, float4 b) {
  union { uint2 u[2]; bf16x8 v; } r;
  r.u[0] = pack4(a);
  r.u[1] = pack4(b);
  return r.v;
}

// ---------------------------------------------------------------------------
// FUSED GRU kernel. One WG (256 thr = 4 waves) per (b,n); grid = 256.
//
// R7 post-mortem: fused structure mechanically sound, failed ONLY on the
// pre-flagged n-gate bias algebra: bhh_n must stay INSIDE the r-product
// (reference: n = tanh(gx_n + bih_n + r*(Wh_n + bhh_n))). Fix: bs_n = bih_n
// only; bh_n held separately and added to ghn0 before the r-multiply.
// r/z gates are symmetric in the two biases -> their fusion stays.
//
// Per chunk c (during its 8 steps, prepare chunk c+1):
//   top:  24 MFMAs (wave's 6 colblocks x 4 kt) compute gates_x for chunk
//         c+1 from X regs loaded a chunk ago -> fp32 into gbuf[c+1 parity]
//         (quads 0,1 hold D rows t=0..7; scatter [s][e*4+{r,z,n}]).
//         Then issue chunk c+2's X loads (per-lane, retire over 8 steps).
//   step: proven v5 structure — one ds_read_b128 gx (fp32 r,z,n,pad),
//         hi/lo h2 A-frags (HPAD bank-split), 24 gates_h MFMAs, fused
//         biases, sigmoid/tanh chain, h2 dbuf write, 1 barrier.
//   end:  batched out stores from update lanes (drain amortized per chunk).
//
// gates_x stays fp32 end-to-end (no bf16 rounding of gates).
// ---------------------------------------------------------------------------
__global__ __launch_bounds__(256, 1) void gru_fused_kernel(
    const float* __restrict__ x, const float* __restrict__ h0,
    const float* __restrict__ w_ih, const float* __restrict__ w_hh,
    const float* __restrict__ b_ih, const float* __restrict__ b_hh,
    float* __restrict__ out) {
  const int b = blockIdx.x >> 4;
  const int n = blockIdx.x & 15;
  const int tid = threadIdx.x;
  const int wave = tid >> 6;
  const int lane = tid & 63;
  const int m16 = lane & 15;
  const int quad = lane >> 4;

  __shared__ __align__(16) unsigned short h2[2][2][HPAD]; // [buf][hi|lo]
  __shared__ __align__(16) float gbuf[2][CHUNK][512];     // [buf][s][e*4+idx]

  // ---- W_hh B-fragments (proven v5 mapping): wave w owns colblocks
  // {2w, 8+2w, 16+2w, 2w+1, 9+2w, 17+2w} = r0,z0,n0,r1,z1,n1 for its elems.
  bf16x8 wf[6][4];
  {
    const int cb0 = 2 * wave;
    const int cbs[6] = {cb0, 8 + cb0, 16 + cb0, cb0 + 1, 9 + cb0, 17 + cb0};
#pragma unroll
    for (int j = 0; j < 6; ++j) {
      const int g = cbs[j] * 16 + m16;
      const float4* wr = (const float4*)(w_hh + ((size_t)n * G3 + g) * H_DIM);
#pragma unroll
      for (int kt = 0; kt < 4; ++kt)
        wf[j][kt] = pack8(wr[kt * 8 + quad * 2], wr[kt * 8 + quad * 2 + 1]);
    }
  }

  // ---- W_ih B-fragments: wave owns gates_x colblocks wave*6+jj (jj 0..5).
  bf16x8 wxf[6][4];
#pragma unroll
  for (int jj = 0; jj < 6; ++jj) {
    const int g = (wave * 6 + jj) * 16 + m16;
    const float4* wr = (const float4*)(w_ih + ((size_t)n * G3 + g) * I_DIM);
#pragma unroll
    for (int kt = 0; kt < 4; ++kt)
      wxf[jj][kt] = pack8(wr[kt * 8 + quad * 2], wr[kt * 8 + quad * 2 + 1]);
  }

  const bool upd = quad < 2;                    // 128 updating lanes
  const int elem = wave * 32 + quad * 16 + m16; // h element owned (if upd)

  // Biases: r/z fuse (symmetric); n-gate keeps bhh_n SEPARATE (inside
  // the r-product, matching reference ordering).
  float bs_r = 0.f, bs_z = 0.f, bs_n = 0.f, bh_n = 0.f, h_old = 0.f;
  if (upd) {
    bs_r = b_ih[n * G3 + elem] + b_hh[n * G3 + elem];
    bs_z = b_ih[n * G3 + elem + 128] + b_hh[n * G3 + elem + 128];
    bs_n = b_ih[n * G3 + elem + 256]; // bih_n only
    bh_n = b_hh[n * G3 + elem + 256]; // stays inside r*( . )
    h_old = h0[(size_t)b * 2048 + n * H_DIM + elem];
    const unsigned short hh = f2bf(h_old);
    h2[0][0][elem] = hh;
    h2[0][1][elem] = f2bf(h_old - bf2f(hh));
  }

  // X A-frag source: lane (m16,quad) covers row t = c*8 + (m16&7),
  // k-slice kt*32 + quad*8 .. +8 (two float4 per kt). Rows 8..15 of the
  // MFMA A-tile duplicate rows 0..7 (their D rows land in quads 2,3: unused).
  const float* xrow_base = x + (size_t)b * T_SZ * 2048 + n * I_DIM +
                           (size_t)(m16 & 7) * 2048 + quad * 8;

  float4 pf[8]; // next-next chunk's X (per-lane), lives one chunk

#define LOAD_X_CHUNK(c)                                                       \
  {                                                                           \
    const float* xr = xrow_base + (size_t)(c) * CHUNK * 2048;                 \
    _Pragma("unroll") for (int kt = 0; kt < 4; ++kt) {                        \
      pf[kt * 2] = *(const float4*)(xr + kt * 32);                            \
      pf[kt * 2 + 1] = *(const float4*)(xr + kt * 32 + 4);                    \
    }                                                                         \
  }

  // Compute gates_x for one chunk from pf -> fp32 scatter into gdst.
#define GATES_X_CHUNK(gdst)                                                   \
  {                                                                           \
    bf16x8 af[4];                                                             \
    _Pragma("unroll") for (int kt = 0; kt < 4; ++kt)                          \
        af[kt] = pack8(pf[kt * 2], pf[kt * 2 + 1]);                           \
    _Pragma("unroll") for (int jj = 0; jj < 6; ++jj) {                        \
      f32x4 a = {0.f, 0.f, 0.f, 0.f};                                         \
      _Pragma("unroll") for (int kt = 0; kt < 4; ++kt)                        \
          a = __builtin_amdgcn_mfma_f32_16x16x32_bf16(af[kt], wxf[jj][kt], a, \
                                                      0, 0, 0);               \
      if (quad < 2) {                                                         \
        const int g = (wave * 6 + jj) * 16 + m16;                             \
        const int e4 = (g & 127) * 4 + (g >> 7);                              \
        _Pragma("unroll") for (int r = 0; r < 4; ++r)                         \
            (gdst)[(quad * 4 + r) * 512 + e4] = a[r];                         \
      }                                                                       \
    }                                                                         \
  }

  // ---- prologue: gates_x chunk 0 staged, chunk 1's X in pf ----
  LOAD_X_CHUNK(0);
  GATES_X_CHUNK(&gbuf[0][0][0]);
  LOAD_X_CHUNK(1);
  __syncthreads();

  float* out_base = out + (size_t)b * T_SZ * 2048 + n * H_DIM;
  float oreg[CHUNK];

  for (int c = 0; c < NCHUNK; ++c) {
    const int gb = c & 1;

    // Chunk top: gates_x for chunk c+1 (from pf = X of chunk c+1), then
    // issue chunk c+2's X loads (retire across this chunk's steps).
    if (c + 1 < NCHUNK) {
      GATES_X_CHUNK(&gbuf[gb ^ 1][0][0]);
      if (c + 2 < NCHUNK) LOAD_X_CHUNK(c + 2);
    }

#pragma unroll
    for (int s = 0; s < CHUNK; ++s) {
      const int rb = s & 1; // chunk length even -> parity restarts at 0
      const int wb = rb ^ 1;

      // gates_x: ONE ds_read_b128 -> {r, z, n, pad} fp32.
      float gxr = 0.f, gxz = 0.f, gxn = 0.f;
      if (upd) {
        const f32x4 g4 = *(const f32x4*)&gbuf[gb][s][elem * 4];
        gxr = g4[0];
        gxz = g4[1];
        gxn = g4[2];
      }

      // h A-fragments (hi for even m16 rows, lo for odd; HPAD bank-split).
      const unsigned short* hsrc = &h2[rb][m16 & 1][0];
      const bf16x8 av0 = *(const bf16x8*)&hsrc[0 * 32 + quad * 8];
      const bf16x8 av1 = *(const bf16x8*)&hsrc[1 * 32 + quad * 8];
      const bf16x8 av2 = *(const bf16x8*)&hsrc[2 * 32 + quad * 8];
      const bf16x8 av3 = *(const bf16x8*)&hsrc[3 * 32 + quad * 8];

      f32x4 acc[6];
#pragma unroll
      for (int j = 0; j < 6; ++j) acc[j] = (f32x4){0.f, 0.f, 0.f, 0.f};
#pragma unroll
      for (int j = 0; j < 6; ++j)
        acc[j] = __builtin_amdgcn_mfma_f32_16x16x32_bf16(av0, wf[j][0], acc[j],
                                                         0, 0, 0);
#pragma unroll
      for (int j = 0; j < 6; ++j)
        acc[j] = __builtin_amdgcn_mfma_f32_16x16x32_bf16(av1, wf[j][1], acc[j],
                                                         0, 0, 0);
#pragma unroll
      for (int j = 0; j < 6; ++j)
        acc[j] = __builtin_amdgcn_mfma_f32_16x16x32_bf16(av2, wf[j][2], acc[j],
                                                         0, 0, 0);
#pragma unroll
      for (int j = 0; j < 6; ++j)
        acc[j] = __builtin_amdgcn_mfma_f32_16x16x32_bf16(av3, wf[j][3], acc[j],
                                                         0, 0, 0);

      if (upd) {
        // D[0] = W.h_hi, D[1] = W.h_lo (rows 0,1 of each quad's 4).
        const float ghr =
            (quad ? acc[3][0] + acc[3][1] : acc[0][0] + acc[0][1]);
        const float ghz =
            (quad ? acc[4][0] + acc[4][1] : acc[1][0] + acc[1][1]);
        const float ghn0 =
            (quad ? acc[5][0] + acc[5][1] : acc[2][0] + acc[2][1]);
        const float r = 1.f / (1.f + __expf(-(gxr + ghr + bs_r)));
        const float z = 1.f / (1.f + __expf(-(gxz + ghz + bs_z)));
        // Reference ordering: n = tanh(gx_n + bih_n + r*(Wh_n + bhh_n)).
        const float targ = gxn + bs_n + r * (ghn0 + bh_n);
        const float rt = 1.f / (1.f + __expf(-2.f * targ)); // sigmoid(2x)
        const float nn = 2.f * rt - 1.f;                    // tanh(targ)
        const float hn = (1.f - z) * nn + z * h_old;
        const unsigned short hh = f2bf(hn);
        h2[wb][0][elem] = hh;
        h2[wb][1][elem] = f2bf(hn - bf2f(hh));
        h_old = hn;
        oreg[s] = hn;
      }
      __syncthreads();
    }

    // Batched out stores (drain amortized at next chunk's first barrier).
    if (upd) {
#pragma unroll
      for (int s = 0; s < CHUNK; ++s)
        out_base[(size_t)(c * CHUNK + s) * 2048 + elem] = oreg[s];
    }
  }

  if (upd) {
    out[OUT_HN_OFFSET + (size_t)b * 2048 + n * H_DIM + elem] = h_old;
  }
}

extern "C" void kernel_launch(void* const* d_in, const int* in_sizes, int n_in,
                              void* d_out, int out_size, void* d_ws,
                              size_t ws_size, hipStream_t stream) {
  const float* x    = (const float*)d_in[0]; // [B, T, N*I]
  const float* h0   = (const float*)d_in[1]; // [1, B, N*H]
  const float* w_ih = (const float*)d_in[2]; // [N, 3H, I]
  const float* w_hh = (const float*)d_in[3]; // [N, 3H, H]
  const float* b_ih = (const float*)d_in[4]; // [N, 3H]
  const float* b_hh = (const float*)d_in[5]; // [N, 3H]
  float* out = (float*)d_out;
  (void)d_ws; // fused kernel: no gates workspace needed

  gru_fused_kernel<<<256, 256, 0, stream>>>(x, h0, w_ih, w_hh, b_ih, b_hh,
                                            out);
}